// Round 1
// baseline (10860.514 us; speedup 1.0000x reference)
//
#include <hip/hip_runtime.h>
#include <hip/hip_fp16.h>

typedef _Float16 f16x8 __attribute__((ext_vector_type(8)));
typedef float f32x4 __attribute__((ext_vector_type(4)));

namespace {
constexpr int BB = 32;    // batch
constexpr int SS = 512;   // seq len
constexpr int HH = 512;   // hidden
constexpr int G4 = 2048;  // 4*H gates
constexpr int NWG = 64;   // workgroups per direction in recurrence
constexpr int UPW = 8;    // hidden units per WG (H / NWG)
}

// ---------------- utility kernels ----------------
__global__ void k_zero(int* __restrict__ p, int n) {
  int i = blockIdx.x * blockDim.x + threadIdx.x;
  if (i < n) p[i] = 0;
}

__global__ void k_cvt(const float* __restrict__ s, _Float16* __restrict__ d, int n) {
  int i = blockIdx.x * blockDim.x + threadIdx.x;
  int stride = gridDim.x * blockDim.x;
  for (; i < n; i += stride) d[i] = (_Float16)s[i];
}

// ---------------- input-projection GEMM ----------------
// gx[dir][t][b][4H] = A[r=(b,t)][K] @ W[dir][4H][K]^T + bih[dir] + bhh[dir]
// A rows are r = b*512 + t (row-major over K). Tile: 128x128, BK=32.
__global__ __launch_bounds__(256) void k_gemm(
    const _Float16* __restrict__ Ain,  // [16384][K]
    const _Float16* __restrict__ W,    // [2][2048][K]
    const float* __restrict__ bih0, const float* __restrict__ bhh0,
    const float* __restrict__ bih1, const float* __restrict__ bhh1,
    _Float16* __restrict__ gx,         // [2][512][32][2048]
    int K) {
  __shared__ _Float16 As[128][40];   // +8 pad (16B) to break bank stride
  __shared__ _Float16 Bs[128][40];
  const int tid = threadIdx.x;
  const int lane = tid & 63, wave = tid >> 6;
  const int dir = blockIdx.z;
  const int r0 = blockIdx.x * 128;
  const int n0 = blockIdx.y * 128;
  const _Float16* Wd = W + (size_t)dir * G4 * K;
  const float* bi = dir ? bih1 : bih0;
  const float* bh = dir ? bhh1 : bhh0;
  const int mw = wave & 1, nw = wave >> 1;  // 2x2 wave grid, each 64x64

  f32x4 acc[4][4];
#pragma unroll
  for (int a = 0; a < 4; ++a)
#pragma unroll
    for (int b = 0; b < 4; ++b) acc[a][b] = (f32x4){0.f, 0.f, 0.f, 0.f};

  const int c1 = tid, c2 = tid + 256;           // 16B chunks of the 128x32 tile
  const int ar1 = c1 >> 2, ak1 = (c1 & 3) * 8;
  const int ar2 = c2 >> 2, ak2 = (c2 & 3) * 8;
  const int fr = lane & 15, fq = (lane >> 4) * 8;

  const int nstage = K >> 5;
  for (int ks = 0; ks < nstage; ++ks) {
    const int k0 = ks << 5;
    *(f16x8*)&As[ar1][ak1] = *(const f16x8*)&Ain[(size_t)(r0 + ar1) * K + k0 + ak1];
    *(f16x8*)&As[ar2][ak2] = *(const f16x8*)&Ain[(size_t)(r0 + ar2) * K + k0 + ak2];
    *(f16x8*)&Bs[ar1][ak1] = *(const f16x8*)&Wd[(size_t)(n0 + ar1) * K + k0 + ak1];
    *(f16x8*)&Bs[ar2][ak2] = *(const f16x8*)&Wd[(size_t)(n0 + ar2) * K + k0 + ak2];
    __syncthreads();
    f16x8 af[4], bf[4];
#pragma unroll
    for (int mt = 0; mt < 4; ++mt) af[mt] = *(const f16x8*)&As[mw * 64 + mt * 16 + fr][fq];
#pragma unroll
    for (int nt = 0; nt < 4; ++nt) bf[nt] = *(const f16x8*)&Bs[nw * 64 + nt * 16 + fr][fq];
#pragma unroll
    for (int mt = 0; mt < 4; ++mt)
#pragma unroll
      for (int nt = 0; nt < 4; ++nt)
        acc[mt][nt] = __builtin_amdgcn_mfma_f32_16x16x32_f16(af[mt], bf[nt], acc[mt][nt], 0, 0, 0);
    __syncthreads();
  }

  // epilogue: D[row][col], col = lane&15, row = (lane>>4)*4 + q  [m89/m91]
  const int q4 = (lane >> 4) * 4;
#pragma unroll
  for (int nt = 0; nt < 4; ++nt) {
    const int col = n0 + nw * 64 + nt * 16 + fr;
    const float bsum = bi[col] + bh[col];
#pragma unroll
    for (int mt = 0; mt < 4; ++mt) {
#pragma unroll
      for (int q = 0; q < 4; ++q) {
        const int r = r0 + mw * 64 + mt * 16 + q4 + q;
        const int b = r >> 9, t = r & 511;
        gx[(((size_t)dir * SS + t) * BB + b) * G4 + col] = (_Float16)(acc[mt][nt][q] + bsum);
      }
    }
  }
}

// ---------------- recurrence (cooperative, 128 WGs = 64 per direction) ----------------
// Each WG owns 8 hidden units for one direction. Whh fragments live in registers,
// cell state lives in one register per thread. Per-step sync: per-step global
// atomic counter (monotonic, no reuse) + write-through h stores.
__global__ __launch_bounds__(256) void k_recur(
    const _Float16* __restrict__ gx,   // [2][512][32][2048]
    const _Float16* __restrict__ Whh,  // [2][2048][512] fp16, this layer
    _Float16* __restrict__ y,          // [32][512][1024] fp16 layer output
    float* __restrict__ outf,          // nullptr, or [32][512][1024] fp32 (layer 1)
    int* __restrict__ cnt) {           // [2][512]
  const int tid = threadIdx.x;
  const int lane = tid & 63, wave = tid >> 6;
  const int wg = blockIdx.x & (NWG - 1);
  const int dir = blockIdx.x >> 6;
  const int m = wave & 1, n = wave >> 1;  // m: batch half, n: gate pair (i|f , g|o)

  __shared__ float gates_s[32][33];
  __shared__ __align__(16) unsigned short h_s[32][8];

  const int c = lane & 15;
  const int quad8 = (lane >> 4) * 8;
  // B-fragment rows: n-tile0 cols 0..7 = i-rows, 8..15 = f-rows; tile1: g, o
  const int cls = n * 2 + (c >> 3);
  const int grow = cls * HH + wg * UPW + (c & 7);
  const _Float16* Wd = Whh + ((size_t)dir * G4 + grow) * HH;
  f16x8 bfrag[16];
#pragma unroll
  for (int kk = 0; kk < 16; ++kk) bfrag[kk] = *(const f16x8*)&Wd[kk * 32 + quad8];

  const int tb = tid >> 3, tu = tid & 7;  // this thread owns (batch tb, unit tu)
  float cstate = 0.f;

  const _Float16* gxd = gx + (size_t)dir * SS * BB * G4;
  int* mycnt = cnt + dir * SS;

  for (int s = 0; s < SS; ++s) {
    const int t = dir ? (SS - 1 - s) : s;
    const int tprev = dir ? (t + 1) : (t - 1);

    f32x4 acc = (f32x4){0.f, 0.f, 0.f, 0.f};
    if (s > 0) {
      if (tid == 0) {
        while (__hip_atomic_load(&mycnt[s - 1], __ATOMIC_RELAXED, __HIP_MEMORY_SCOPE_AGENT) < NWG) {}
      }
      __syncthreads();
      __builtin_amdgcn_fence(__ATOMIC_ACQUIRE, "agent");
      // A-fragments of h(t_prev): A[m=lane&15][k=quad*8+j]
      const _Float16* hrow = y + ((size_t)(m * 16 + c) * SS + tprev) * 1024 + dir * HH;
      f16x8 af[16];
#pragma unroll
      for (int kk = 0; kk < 16; ++kk) af[kk] = *(const f16x8*)&hrow[kk * 32 + quad8];
#pragma unroll
      for (int kk = 0; kk < 16; ++kk)
        acc = __builtin_amdgcn_mfma_f32_16x16x32_f16(af[kk], bfrag[kk], acc, 0, 0, 0);
    }
    // scatter gate tile to LDS: D col = lane&15, row = (lane>>4)*4+q
#pragma unroll
    for (int q = 0; q < 4; ++q) gates_s[m * 16 + (lane >> 4) * 4 + q][n * 16 + c] = acc[q];
    __syncthreads();

    const _Float16* gq = gxd + ((size_t)t * BB + tb) * G4 + wg * UPW + tu;
    const float ip = gates_s[tb][tu] + (float)gq[0];
    const float fp = gates_s[tb][8 + tu] + (float)gq[HH];
    const float gp = gates_s[tb][16 + tu] + (float)gq[2 * HH];
    const float op = gates_s[tb][24 + tu] + (float)gq[3 * HH];
    const float iv = 1.f / (1.f + __expf(-ip));
    const float fv = 1.f / (1.f + __expf(-fp));
    const float gv = tanhf(gp);
    const float ov = 1.f / (1.f + __expf(-op));
    cstate = fv * cstate + iv * gv;
    const float hv = ov * tanhf(cstate);
    {
      const _Float16 hh = (_Float16)hv;
      h_s[tb][tu] = __builtin_bit_cast(unsigned short, hh);
    }
    if (outf) outf[((size_t)tb * SS + t) * 1024 + dir * HH + wg * UPW + tu] = hv;
    __syncthreads();  // h_s ready

    if (tid < 32) {  // pack 8 fp16 -> two 8B write-through stores
      const uint4 hv4 = *(const uint4*)&h_s[tid][0];
      const unsigned long long lo = ((unsigned long long)hv4.y << 32) | hv4.x;
      const unsigned long long hi = ((unsigned long long)hv4.w << 32) | hv4.z;
      unsigned long long* dst =
          (unsigned long long*)(y + ((size_t)tid * SS + t) * 1024 + dir * HH + wg * UPW);
      __hip_atomic_store(dst, lo, __ATOMIC_RELAXED, __HIP_MEMORY_SCOPE_AGENT);
      __hip_atomic_store(dst + 1, hi, __ATOMIC_RELAXED, __HIP_MEMORY_SCOPE_AGENT);
    }
    __syncthreads();  // drains vmcnt(0) in every wave before the flag
    if (tid == 0) {
      __builtin_amdgcn_fence(__ATOMIC_RELEASE, "agent");
      __hip_atomic_fetch_add(&mycnt[s], 1, __ATOMIC_RELAXED, __HIP_MEMORY_SCOPE_AGENT);
    }
  }
}

// ---------------- launch ----------------
extern "C" void kernel_launch(void* const* d_in, const int* in_sizes, int n_in,
                              void* d_out, int out_size, void* d_ws, size_t ws_size,
                              hipStream_t stream) {
  (void)in_sizes; (void)n_in; (void)out_size; (void)ws_size;
  const float* x = (const float*)d_in[0];
  // dict order: x, then per (layer, dir): Wih, Whh, bih, bhh
  const float* Wih[4] = {(const float*)d_in[1], (const float*)d_in[5],
                         (const float*)d_in[9], (const float*)d_in[13]};
  const float* Whh[4] = {(const float*)d_in[2], (const float*)d_in[6],
                         (const float*)d_in[10], (const float*)d_in[14]};
  const float* bih[4] = {(const float*)d_in[3], (const float*)d_in[7],
                         (const float*)d_in[11], (const float*)d_in[15]};
  const float* bhh[4] = {(const float*)d_in[4], (const float*)d_in[8],
                         (const float*)d_in[12], (const float*)d_in[16]};

  char* p = (char*)d_ws;
  auto take = [&](size_t bytes) { char* r = p; p += (bytes + 255) & ~(size_t)255; return r; };
  _Float16* x16  = (_Float16*)take((size_t)BB * SS * 512 * 2);   // 16.8 MB
  _Float16* wih0 = (_Float16*)take((size_t)2 * G4 * 512 * 2);    // 4.2 MB
  _Float16* wih1 = (_Float16*)take((size_t)2 * G4 * 1024 * 2);   // 8.4 MB
  _Float16* whh16 = (_Float16*)take((size_t)4 * G4 * 512 * 2);   // 8.4 MB
  _Float16* gx   = (_Float16*)take((size_t)2 * SS * BB * G4 * 2); // 134 MB (reused per layer)
  _Float16* y0   = (_Float16*)take((size_t)BB * SS * 1024 * 2);  // 33.6 MB
  _Float16* y1   = (_Float16*)take((size_t)BB * SS * 1024 * 2);  // 33.6 MB
  int* cnt       = (int*)take((size_t)2 * 2 * SS * 4);           // 8 KB

  hipLaunchKernelGGL(k_zero, dim3(8), dim3(256), 0, stream, cnt, 2 * 2 * SS);
  hipLaunchKernelGGL(k_cvt, dim3(512), dim3(256), 0, stream, x, x16, BB * SS * 512);
  hipLaunchKernelGGL(k_cvt, dim3(128), dim3(256), 0, stream, Wih[0], wih0, G4 * 512);
  hipLaunchKernelGGL(k_cvt, dim3(128), dim3(256), 0, stream, Wih[1], wih0 + (size_t)G4 * 512, G4 * 512);
  hipLaunchKernelGGL(k_cvt, dim3(256), dim3(256), 0, stream, Wih[2], wih1, G4 * 1024);
  hipLaunchKernelGGL(k_cvt, dim3(256), dim3(256), 0, stream, Wih[3], wih1 + (size_t)G4 * 1024, G4 * 1024);
  for (int i = 0; i < 4; ++i)
    hipLaunchKernelGGL(k_cvt, dim3(128), dim3(256), 0, stream, Whh[i],
                       whh16 + (size_t)i * G4 * 512, G4 * 512);

  // layer 0
  hipLaunchKernelGGL(k_gemm, dim3(128, 16, 2), dim3(256), 0, stream,
                     x16, wih0, bih[0], bhh[0], bih[1], bhh[1], gx, 512);
  {
    const _Float16* gxp = gx; const _Float16* whhp = whh16;
    _Float16* yp = y0; float* op = nullptr; int* cp = cnt;
    void* args[] = {&gxp, &whhp, &yp, &op, &cp};
    hipLaunchCooperativeKernel((const void*)k_recur, dim3(2 * NWG), dim3(256), args, 0, stream);
  }
  // layer 1
  hipLaunchKernelGGL(k_gemm, dim3(128, 16, 2), dim3(256), 0, stream,
                     y0, wih1, bih[2], bhh[2], bih[3], bhh[3], gx, 1024);
  {
    const _Float16* gxp = gx; const _Float16* whhp = whh16 + (size_t)2 * G4 * 512;
    _Float16* yp = y1; float* op = (float*)d_out; int* cp = cnt + 2 * SS;
    void* args[] = {&gxp, &whhp, &yp, &op, &cp};
    hipLaunchCooperativeKernel((const void*)k_recur, dim3(2 * NWG), dim3(256), args, 0, stream);
  }
}

// Round 2
// 9123.441 us; speedup vs baseline: 1.1904x; 1.1904x over previous
//
#include <hip/hip_runtime.h>
#include <hip/hip_fp16.h>

typedef _Float16 f16x8 __attribute__((ext_vector_type(8)));
typedef float f32x4 __attribute__((ext_vector_type(4)));

namespace {
constexpr int BB = 32;    // batch
constexpr int SS = 512;   // seq len
constexpr int HH = 512;   // hidden
constexpr int G4 = 2048;  // 4*H gates
constexpr int NWG = 64;   // workgroups per direction in recurrence
constexpr int UPW = 8;    // hidden units per WG (H / NWG)
constexpr int FPAD = 16;  // flag padding: 16 ints = 64B, one cache line per flag
}

// ---------------- utility kernels ----------------
__global__ void k_zero(int* __restrict__ p, int n) {
  int i = blockIdx.x * blockDim.x + threadIdx.x;
  if (i < n) p[i] = 0;
}

__global__ void k_cvt(const float* __restrict__ s, _Float16* __restrict__ d, int n) {
  int i = blockIdx.x * blockDim.x + threadIdx.x;
  int stride = gridDim.x * blockDim.x;
  for (; i < n; i += stride) d[i] = (_Float16)s[i];
}

// ---------------- input-projection GEMM ----------------
// gx[dir][t][b][4H] = A[r=(b,t)][K] @ W[dir][4H][K]^T + bih[dir] + bhh[dir]
__global__ __launch_bounds__(256) void k_gemm(
    const _Float16* __restrict__ Ain,  // [16384][K]
    const _Float16* __restrict__ W,    // [2][2048][K]
    const float* __restrict__ bih0, const float* __restrict__ bhh0,
    const float* __restrict__ bih1, const float* __restrict__ bhh1,
    _Float16* __restrict__ gx,         // [2][512][32][2048]
    int K) {
  __shared__ _Float16 As[128][40];
  __shared__ _Float16 Bs[128][40];
  const int tid = threadIdx.x;
  const int lane = tid & 63, wave = tid >> 6;
  const int dir = blockIdx.z;
  const int r0 = blockIdx.x * 128;
  const int n0 = blockIdx.y * 128;
  const _Float16* Wd = W + (size_t)dir * G4 * K;
  const float* bi = dir ? bih1 : bih0;
  const float* bh = dir ? bhh1 : bhh0;
  const int mw = wave & 1, nw = wave >> 1;

  f32x4 acc[4][4];
#pragma unroll
  for (int a = 0; a < 4; ++a)
#pragma unroll
    for (int b = 0; b < 4; ++b) acc[a][b] = (f32x4){0.f, 0.f, 0.f, 0.f};

  const int c1 = tid, c2 = tid + 256;
  const int ar1 = c1 >> 2, ak1 = (c1 & 3) * 8;
  const int ar2 = c2 >> 2, ak2 = (c2 & 3) * 8;
  const int fr = lane & 15, fq = (lane >> 4) * 8;

  const int nstage = K >> 5;
  for (int ks = 0; ks < nstage; ++ks) {
    const int k0 = ks << 5;
    *(f16x8*)&As[ar1][ak1] = *(const f16x8*)&Ain[(size_t)(r0 + ar1) * K + k0 + ak1];
    *(f16x8*)&As[ar2][ak2] = *(const f16x8*)&Ain[(size_t)(r0 + ar2) * K + k0 + ak2];
    *(f16x8*)&Bs[ar1][ak1] = *(const f16x8*)&Wd[(size_t)(n0 + ar1) * K + k0 + ak1];
    *(f16x8*)&Bs[ar2][ak2] = *(const f16x8*)&Wd[(size_t)(n0 + ar2) * K + k0 + ak2];
    __syncthreads();
    f16x8 af[4], bf[4];
#pragma unroll
    for (int mt = 0; mt < 4; ++mt) af[mt] = *(const f16x8*)&As[mw * 64 + mt * 16 + fr][fq];
#pragma unroll
    for (int nt = 0; nt < 4; ++nt) bf[nt] = *(const f16x8*)&Bs[nw * 64 + nt * 16 + fr][fq];
#pragma unroll
    for (int mt = 0; mt < 4; ++mt)
#pragma unroll
      for (int nt = 0; nt < 4; ++nt)
        acc[mt][nt] = __builtin_amdgcn_mfma_f32_16x16x32_f16(af[mt], bf[nt], acc[mt][nt], 0, 0, 0);
    __syncthreads();
  }

  const int q4 = (lane >> 4) * 4;
#pragma unroll
  for (int nt = 0; nt < 4; ++nt) {
    const int col = n0 + nw * 64 + nt * 16 + fr;
    const float bsum = bi[col] + bh[col];
#pragma unroll
    for (int mt = 0; mt < 4; ++mt) {
#pragma unroll
      for (int q = 0; q < 4; ++q) {
        const int r = r0 + mw * 64 + mt * 16 + q4 + q;
        const int b = r >> 9, t = r & 511;
        gx[(((size_t)dir * SS + t) * BB + b) * G4 + col] = (_Float16)(acc[mt][nt][q] + bsum);
      }
    }
  }
}

// ---------------- recurrence (cooperative, 128 WGs = 64 per direction) ----------------
// Per-WG flag array (64B-padded) instead of one contended counter; h loads are
// agent-scope atomic (bypass stale per-XCD L2 -> read L3, the coherence point)
// so no per-step acquire fence / L2 invalidate is needed. h is stored directly
// per-thread as 2B write-through atomics (no LDS pack phase). 3 barriers/step.
__global__ __launch_bounds__(256) void k_recur(
    const _Float16* __restrict__ gx,   // [2][512][32][2048]
    const _Float16* __restrict__ Whh,  // [2][2048][512] fp16, this layer
    _Float16* __restrict__ y,          // [32][512][1024] fp16 layer output
    float* __restrict__ outf,          // nullptr, or [32][512][1024] fp32 (layer 1)
    int* __restrict__ flags) {         // [2][NWG*FPAD]
  const int tid = threadIdx.x;
  const int lane = tid & 63, wave = tid >> 6;
  const int wg = blockIdx.x & (NWG - 1);
  const int dir = blockIdx.x >> 6;
  const int m = wave & 1, n = wave >> 1;  // m: batch half, n: gate pair

  __shared__ float gates_s[32][33];

  const int c = lane & 15;
  const int quad8 = (lane >> 4) * 8;
  const int cls = n * 2 + (c >> 3);
  const int grow = cls * HH + wg * UPW + (c & 7);
  const _Float16* Wd = Whh + ((size_t)dir * G4 + grow) * HH;
  f16x8 bfrag[16];
#pragma unroll
  for (int kk = 0; kk < 16; ++kk) bfrag[kk] = *(const f16x8*)&Wd[kk * 32 + quad8];

  const int tb = tid >> 3, tu = tid & 7;  // this thread owns (batch tb, unit tu)
  float cstate = 0.f;

  const _Float16* gxd = gx + (size_t)dir * SS * BB * G4;
  int* fl = flags + dir * (NWG * FPAD);
  const size_t ycol = (size_t)dir * HH + wg * UPW + tu;

  struct U2 { unsigned long long a, b; };

  for (int s = 0; s < SS; ++s) {
    const int t = dir ? (SS - 1 - s) : s;
    const int tprev = dir ? (t + 1) : (t - 1);

    // gx gate inputs: independent of h, issue before the wait to overlap.
    const _Float16* gq = gxd + ((size_t)t * BB + tb) * G4 + wg * UPW + tu;
    const float gxi = (float)gq[0];
    const float gxf = (float)gq[HH];
    const float gxg = (float)gq[2 * HH];
    const float gxo = (float)gq[3 * HH];

    f32x4 acc = (f32x4){0.f, 0.f, 0.f, 0.f};
    if (s > 0) {
      if (wave == 0) {  // 64 lanes poll 64 per-WG flags in parallel
        while (true) {
          const int v = __hip_atomic_load(&fl[lane * FPAD], __ATOMIC_RELAXED,
                                          __HIP_MEMORY_SCOPE_AGENT);
          if (__all(v >= s)) break;
        }
      }
      __syncthreads();  // B1
      __atomic_signal_fence(__ATOMIC_ACQUIRE);
      // A-fragments of h(t_prev) via coherent 8B loads (L3 read, no fence).
      const _Float16* hrow = y + ((size_t)(m * 16 + c) * SS + tprev) * 1024 + dir * HH;
      const unsigned long long* h64 = (const unsigned long long*)hrow;
      const int qo = quad8 >> 2;
      f16x8 af[16];
#pragma unroll
      for (int kk = 0; kk < 16; ++kk) {
        U2 u;
        u.a = __hip_atomic_load(h64 + kk * 8 + qo, __ATOMIC_RELAXED, __HIP_MEMORY_SCOPE_AGENT);
        u.b = __hip_atomic_load(h64 + kk * 8 + qo + 1, __ATOMIC_RELAXED, __HIP_MEMORY_SCOPE_AGENT);
        af[kk] = __builtin_bit_cast(f16x8, u);
      }
      f32x4 a0 = (f32x4){0.f, 0.f, 0.f, 0.f};
      f32x4 a1 = (f32x4){0.f, 0.f, 0.f, 0.f};
#pragma unroll
      for (int kk = 0; kk < 16; kk += 2) {
        a0 = __builtin_amdgcn_mfma_f32_16x16x32_f16(af[kk], bfrag[kk], a0, 0, 0, 0);
        a1 = __builtin_amdgcn_mfma_f32_16x16x32_f16(af[kk + 1], bfrag[kk + 1], a1, 0, 0, 0);
      }
      acc = a0 + a1;
    }
    // scatter gate tile to LDS: D col = lane&15, row = (lane>>4)*4+q
#pragma unroll
    for (int q = 0; q < 4; ++q) gates_s[m * 16 + (lane >> 4) * 4 + q][n * 16 + c] = acc[q];
    __syncthreads();  // B2

    const float ip = gates_s[tb][tu] + gxi;
    const float fp = gates_s[tb][8 + tu] + gxf;
    const float gp = gates_s[tb][16 + tu] + gxg;
    const float op = gates_s[tb][24 + tu] + gxo;
    const float iv = 1.f / (1.f + __expf(-ip));
    const float fv = 1.f / (1.f + __expf(-fp));
    const float gv = tanhf(gp);
    const float ov = 1.f / (1.f + __expf(-op));
    cstate = fv * cstate + iv * gv;
    const float hv = ov * tanhf(cstate);

    // direct per-thread write-through stores (2B h, 4B fp32 out)
    const size_t yidx = ((size_t)tb * SS + t) * 1024 + ycol;
    const unsigned short hb = __builtin_bit_cast(unsigned short, (_Float16)hv);
    __hip_atomic_store((unsigned short*)(y + yidx), hb, __ATOMIC_RELAXED,
                       __HIP_MEMORY_SCOPE_AGENT);
    if (outf)
      __hip_atomic_store((unsigned int*)(outf + yidx), __builtin_bit_cast(unsigned int, hv),
                         __ATOMIC_RELAXED, __HIP_MEMORY_SCOPE_AGENT);
    __atomic_signal_fence(__ATOMIC_RELEASE);
    __syncthreads();  // B3: every wave drains vmcnt(0) before s_barrier
    if (tid == 0) {
      __builtin_amdgcn_fence(__ATOMIC_RELEASE, "agent");  // cheap post-barrier; belt & braces
      __hip_atomic_store(&fl[wg * FPAD], s + 1, __ATOMIC_RELAXED, __HIP_MEMORY_SCOPE_AGENT);
    }
  }
}

// ---------------- launch ----------------
extern "C" void kernel_launch(void* const* d_in, const int* in_sizes, int n_in,
                              void* d_out, int out_size, void* d_ws, size_t ws_size,
                              hipStream_t stream) {
  (void)in_sizes; (void)n_in; (void)out_size; (void)ws_size;
  const float* x = (const float*)d_in[0];
  const float* Wih[4] = {(const float*)d_in[1], (const float*)d_in[5],
                         (const float*)d_in[9], (const float*)d_in[13]};
  const float* Whh[4] = {(const float*)d_in[2], (const float*)d_in[6],
                         (const float*)d_in[10], (const float*)d_in[14]};
  const float* bih[4] = {(const float*)d_in[3], (const float*)d_in[7],
                         (const float*)d_in[11], (const float*)d_in[15]};
  const float* bhh[4] = {(const float*)d_in[4], (const float*)d_in[8],
                         (const float*)d_in[12], (const float*)d_in[16]};

  char* p = (char*)d_ws;
  auto take = [&](size_t bytes) { char* r = p; p += (bytes + 255) & ~(size_t)255; return r; };
  _Float16* x16  = (_Float16*)take((size_t)BB * SS * 512 * 2);
  _Float16* wih0 = (_Float16*)take((size_t)2 * G4 * 512 * 2);
  _Float16* wih1 = (_Float16*)take((size_t)2 * G4 * 1024 * 2);
  _Float16* whh16 = (_Float16*)take((size_t)4 * G4 * 512 * 2);
  _Float16* gx   = (_Float16*)take((size_t)2 * SS * BB * G4 * 2);
  _Float16* y0   = (_Float16*)take((size_t)BB * SS * 1024 * 2);
  _Float16* y1   = (_Float16*)take((size_t)BB * SS * 1024 * 2);
  int* flags     = (int*)take((size_t)2 * 2 * NWG * FPAD * 4);  // 2 layers x 2 dirs

  hipLaunchKernelGGL(k_zero, dim3(16), dim3(256), 0, stream, flags, 2 * 2 * NWG * FPAD);
  hipLaunchKernelGGL(k_cvt, dim3(512), dim3(256), 0, stream, x, x16, BB * SS * 512);
  hipLaunchKernelGGL(k_cvt, dim3(128), dim3(256), 0, stream, Wih[0], wih0, G4 * 512);
  hipLaunchKernelGGL(k_cvt, dim3(128), dim3(256), 0, stream, Wih[1], wih0 + (size_t)G4 * 512, G4 * 512);
  hipLaunchKernelGGL(k_cvt, dim3(256), dim3(256), 0, stream, Wih[2], wih1, G4 * 1024);
  hipLaunchKernelGGL(k_cvt, dim3(256), dim3(256), 0, stream, Wih[3], wih1 + (size_t)G4 * 1024, G4 * 1024);
  for (int i = 0; i < 4; ++i)
    hipLaunchKernelGGL(k_cvt, dim3(128), dim3(256), 0, stream, Whh[i],
                       whh16 + (size_t)i * G4 * 512, G4 * 512);

  // layer 0
  hipLaunchKernelGGL(k_gemm, dim3(128, 16, 2), dim3(256), 0, stream,
                     x16, wih0, bih[0], bhh[0], bih[1], bhh[1], gx, 512);
  {
    const _Float16* gxp = gx; const _Float16* whhp = whh16;
    _Float16* yp = y0; float* op = nullptr; int* cp = flags;
    void* args[] = {&gxp, &whhp, &yp, &op, &cp};
    hipLaunchCooperativeKernel((const void*)k_recur, dim3(2 * NWG), dim3(256), args, 0, stream);
  }
  // layer 1
  hipLaunchKernelGGL(k_gemm, dim3(128, 16, 2), dim3(256), 0, stream,
                     y0, wih1, bih[2], bhh[2], bih[3], bhh[3], gx, 1024);
  {
    const _Float16* gxp = gx; const _Float16* whhp = whh16 + (size_t)2 * G4 * 512;
    _Float16* yp = y1; float* op = (float*)d_out; int* cp = flags + 2 * NWG * FPAD;
    void* args[] = {&gxp, &whhp, &yp, &op, &cp};
    hipLaunchCooperativeKernel((const void*)k_recur, dim3(2 * NWG), dim3(256), args, 0, stream);
  }
}